// Round 1
// baseline (787.550 us; speedup 1.0000x reference)
//
#include <hip/hip_runtime.h>
#include <stdint.h>

#define NPOS 2048
#define LN_EPS 1e-5f

typedef short short8 __attribute__((ext_vector_type(8)));
typedef float floatx4 __attribute__((ext_vector_type(4)));

__device__ __forceinline__ uint32_t bf16_rne(float f) {
  uint32_t u = __float_as_uint(f);
  return (u + 0x7fffu + ((u >> 16) & 1u)) >> 16;
}
__device__ __forceinline__ uint32_t pack2(float lo, float hi) {
  return bf16_rne(lo) | (bf16_rne(hi) << 16);
}

// out[r, d, h] = ( rs*invT * dot(x_row*gamma, w[:,h,d])
//                 - mu*rs*invT * c1[h] + (c2[h] + b1[d,h])*invT )
// where c1[h] = sum_m gamma[m] w[m,h,d], c2[h] = sum_m beta[m] w[m,h,d]
__global__ __launch_bounds__(256) void superlinear_kernel(
    const float* __restrict__ x,
    const float* __restrict__ w1,
    const float* __restrict__ b1,
    const float* __restrict__ T,
    const float* __restrict__ gamma,
    const float* __restrict__ beta,
    float* __restrict__ out)
{
  // X tile: 128 rows x 128 k, bf16, A-fragment order:
  //   region = rtile*4 + ktile (rtile=row>>4, ktile=k>>5), 64 chunks x 16B,
  //   logical chunk c = (k8)*16 + r16  (k8=(k&31)>>3, r16=row&15),
  //   physical chunk p = c ^ (k8<<1) ^ ((ktile&1)<<2) ^ (ktile>>1)  [bank swizzle]
  __shared__ uint4 Xs[32 * 64];   // 32 KB
  // G tile: 128 k x 32 h, bf16, B-fragment order:
  //   region = ktile*2 + ht, chunk = kq*16 + n (kq=(k&31)>>3, n=h&15), j = k&7
  __shared__ uint4 Gs[8 * 64];    // 8 KB
  __shared__ float2 stats[128];   // (rs*invT, mu*rs*invT) per local row
  __shared__ __align__(16) float gam[128];
  __shared__ __align__(16) float bet[128];
  __shared__ float c1s[32], es[32];

  const int d = blockIdx.x;
  const int t = threadIdx.x;
  const float invT = 1.0f / T[0];

  // ---------- Phase A: stage gamma/beta; gather W_d into B-frag LDS ----------
  if (t < 32)      ((float4*)gam)[t]      = ((const float4*)gamma)[t];
  else if (t < 64) ((float4*)bet)[t - 32] = ((const float4*)beta)[t - 32];

  {
    const int region = t >> 5;             // 0..7
    const int ktile = region >> 1, ht = region & 1;
#pragma unroll
    for (int cc = 0; cc < 2; ++cc) {
      const int cw = ((t & 31) << 1) | cc; // chunk 0..63
      const int kq = cw >> 4, n = cw & 15;
      const int h = ht * 16 + n;
      const int mb = ktile * 32 + kq * 8;
      const float* wp = w1 + (size_t)mb * (32 * NPOS) + (size_t)h * NPOS + d;
      uint4 v;
      v.x = pack2(wp[0 * 65536], wp[1 * 65536]);
      v.y = pack2(wp[2 * 65536], wp[3 * 65536]);
      v.z = pack2(wp[4 * 65536], wp[5 * 65536]);
      v.w = pack2(wp[6 * 65536], wp[7 * 65536]);
      Gs[region * 64 + cw] = v;
    }
  }
  __syncthreads();

  // ---------- c1/c2 per output column h (threads 0..31) ----------
  if (t < 32) {
    const int ht = t >> 4, n = t & 15;
    const unsigned short* Gu = (const unsigned short*)Gs;
    float c1 = 0.f, c2 = 0.f;
#pragma unroll 8
    for (int m = 0; m < 128; ++m) {
      const int ktile = m >> 5, kq = (m >> 3) & 3, j = m & 7;
      const float w = __uint_as_float((uint32_t)Gu[(ktile * 2 + ht) * 512 + (kq * 16 + n) * 8 + j] << 16);
      c1 = fmaf(gam[m], w, c1);
      c2 = fmaf(bet[m], w, c2);
    }
    c1s[t] = c1;
    es[t] = (c2 + b1[d * 32 + t]) * invT;
  }

  // per-thread gamma registers for staging (cols fixed per thread)
  const int c0 = (t & 15) * 8;
  const float4 ga = ((const float4*)(gam + c0))[0];
  const float4 gb = ((const float4*)(gam + c0))[1];

  const int wv = t >> 6, L = t & 63, quad = L >> 4;
  const short8* Gs8 = (const short8*)Gs;
  const short8* Xs8 = (const short8*)Xs;

  for (int ti = 0; ti < 4; ++ti) {
    // ---------- stage 128 rows of x: coalesced load, LN stats, gamma-fold, bf16 pack ----------
    const int r16 = t >> 4;   // row-within-16 handled by this thread
#pragma unroll
    for (int it = 0; it < 8; ++it) {
      const int lrow = it * 16 + r16;                 // 0..127
      const float* xp = x + (size_t)(ti * 128 + lrow) * (NPOS * 128) + (size_t)d * 128 + c0;
      const float4 xa = ((const float4*)xp)[0];
      const float4 xb = ((const float4*)xp)[1];
      float s1 = xa.x + xa.y + xa.z + xa.w + xb.x + xb.y + xb.z + xb.w;
      float s2 = xa.x * xa.x + xa.y * xa.y + xa.z * xa.z + xa.w * xa.w
               + xb.x * xb.x + xb.y * xb.y + xb.z * xb.z + xb.w * xb.w;
#pragma unroll
      for (int msk = 1; msk < 16; msk <<= 1) {
        s1 += __shfl_xor(s1, msk, 64);
        s2 += __shfl_xor(s2, msk, 64);
      }
      if ((t & 15) == 0) {
        const float mu = s1 * (1.0f / 128.f);
        const float var = fmaf(-mu, mu, s2 * (1.0f / 128.f));
        const float rs = rsqrtf(var + LN_EPS);
        stats[lrow] = make_float2(rs * invT, mu * rs * invT);
      }
      uint4 v;
      v.x = pack2(xa.x * ga.x, xa.y * ga.y);
      v.y = pack2(xa.z * ga.z, xa.w * ga.w);
      v.z = pack2(xb.x * gb.x, xb.y * gb.y);
      v.w = pack2(xb.z * gb.z, xb.w * gb.w);
      const int ktile = (t & 15) >> 2, k8 = t & 3;
      const int c = k8 * 16 + r16;
      const int p = c ^ (k8 << 1) ^ ((ktile & 1) << 2) ^ (ktile >> 1);
      Xs[(it * 4 + ktile) * 64 + p] = v;
    }
    __syncthreads();

    // ---------- MFMA + fused LN/bias/T epilogue ----------
#pragma unroll
    for (int ht = 0; ht < 2; ++ht) {
      short8 bfr[4];
#pragma unroll
      for (int kt = 0; kt < 4; ++kt) bfr[kt] = Gs8[(kt * 2 + ht) * 64 + L];
      const int h = ht * 16 + (L & 15);
      const float c1v = c1s[h], ev = es[h];
#pragma unroll
      for (int rt = 0; rt < 2; ++rt) {
        const int rtile = wv * 2 + rt;
        floatx4 acc = {0.f, 0.f, 0.f, 0.f};
#pragma unroll
        for (int kt = 0; kt < 4; ++kt) {
          const int p = L ^ ((L >> 4) << 1) ^ ((kt & 1) << 2) ^ (kt >> 1);
          const short8 afr = Xs8[(rtile * 4 + kt) * 64 + p];
          acc = __builtin_amdgcn_mfma_f32_16x16x32_bf16(afr, bfr[kt], acc, 0, 0, 0);
        }
        const int lr0 = rtile * 16 + quad * 4;
#pragma unroll
        for (int r = 0; r < 4; ++r) {
          const float2 st = stats[lr0 + r];
          const float val = fmaf(st.x, acc[r], fmaf(-st.y, c1v, ev));
          out[(size_t)(ti * 128 + lr0 + r) * (NPOS * 32) + (size_t)d * 32 + h] = val;
        }
      }
    }
    __syncthreads();
  }
}

extern "C" void kernel_launch(void* const* d_in, const int* in_sizes, int n_in,
                              void* d_out, int out_size, void* d_ws, size_t ws_size,
                              hipStream_t stream) {
  const float* x     = (const float*)d_in[0];
  const float* w1    = (const float*)d_in[1];
  const float* b1    = (const float*)d_in[2];
  const float* T     = (const float*)d_in[3];
  const float* gamma = (const float*)d_in[4];
  const float* beta  = (const float*)d_in[5];
  float* out = (float*)d_out;
  hipLaunchKernelGGL(superlinear_kernel, dim3(NPOS), dim3(256), 0, stream,
                     x, w1, b1, T, gamma, beta, out);
}

// Round 2
// 778.178 us; speedup vs baseline: 1.0120x; 1.0120x over previous
//
#include <hip/hip_runtime.h>
#include <hip/hip_bf16.h>
#include <stdint.h>

#define NPOS 2048
#define LN_EPS 1e-5f

typedef short short8 __attribute__((ext_vector_type(8)));
typedef float floatx4 __attribute__((ext_vector_type(4)));

__device__ __forceinline__ uint32_t packbf2(float lo, float hi) {
  __hip_bfloat162 h = __float22bfloat162_rn(make_float2(lo, hi));
  uint32_t u;
  __builtin_memcpy(&u, &h, 4);
  return u;
}

// ---------------------------------------------------------------------------
// Kernel 1: pack w1[m,h,d] (fp32) -> per-d bf16 B-fragment tiles in ws.
// Layout per d (8 KB = 512 uint4): index = region*64 + chunk,
//   region = ktile*2 + ht (ktile=m>>5, ht=h>>4), chunk = kq*16 + n
//   (kq=(m>>3)&3, n=h&15), j=m&7 packed pairwise into the uint4.
// Reads are d-coalesced (lane = d), 33.5 MB once.
// ---------------------------------------------------------------------------
__global__ __launch_bounds__(256) void wpack_kernel(
    const float* __restrict__ w1, uint4* __restrict__ wp)
{
  const int dlane = threadIdx.x & 63;
  const int sub   = threadIdx.x >> 6;     // 0..3
  const int dg    = blockIdx.x >> 4;      // 0..31
  const int cg    = blockIdx.x & 15;      // 0..15
  const int d     = dg * 64 + dlane;
#pragma unroll
  for (int i = 0; i < 8; ++i) {
    const int chunkid = (cg * 4 + sub) * 8 + i;   // 0..511
    const int region = chunkid >> 6, chunk = chunkid & 63;
    const int ktile = region >> 1, ht = region & 1;
    const int kq = chunk >> 4, n = chunk & 15;
    const int h  = ht * 16 + n;
    const int mb = ktile * 32 + kq * 8;
    const float* src = w1 + (size_t)mb * (32 * NPOS) + (size_t)h * NPOS + d;
    uint4 v;
    v.x = packbf2(src[0 * 65536], src[1 * 65536]);
    v.y = packbf2(src[2 * 65536], src[3 * 65536]);
    v.z = packbf2(src[4 * 65536], src[5 * 65536]);
    v.w = packbf2(src[6 * 65536], src[7 * 65536]);
    wp[(size_t)d * 512 + chunkid] = v;
  }
}

// ---------------------------------------------------------------------------
// Kernel 2: c1[h,d] = sum_m gamma[m] w1[m,h,d]
//           e[h,d]  = (sum_m beta[m] w1[m,h,d] + b1[d,h]) / T
// Fully d-coalesced reads (consecutive tid = consecutive d).
// ---------------------------------------------------------------------------
__global__ __launch_bounds__(256) void c12_kernel(
    const float* __restrict__ w1, const float* __restrict__ b1,
    const float* __restrict__ T, const float* __restrict__ gamma,
    const float* __restrict__ beta,
    float* __restrict__ c1g, float* __restrict__ eg)
{
  const int tid = blockIdx.x * 256 + threadIdx.x;  // 0..65535
  const int d = tid & (NPOS - 1);
  const int h = tid >> 11;                         // 0..31 (uniform per block)
  float c1 = 0.f, c2 = 0.f;
#pragma unroll 8
  for (int m = 0; m < 128; ++m) {
    const float w = w1[(size_t)(m * 32 + h) * NPOS + d];
    c1 = fmaf(gamma[m], w, c1);
    c2 = fmaf(beta[m], w, c2);
  }
  c1g[tid] = c1;
  eg[tid] = (c2 + b1[d * 32 + h]) / T[0];
}

// ---------------------------------------------------------------------------
// Main kernel: one block per position d. Fused LN (folded into epilogue) +
// 512x128x32 bf16-MFMA GEMM.
// out[r,d,h] = rs*invT * dot(x_r*gamma, w[:,h,d]) - mu*rs*invT*c1[h,d] + e[h,d]
// ---------------------------------------------------------------------------
__global__ __launch_bounds__(256, 3) void superlinear_kernel(
    const float* __restrict__ x,
    const uint4* __restrict__ wp,
    const float* __restrict__ c1g,
    const float* __restrict__ eg,
    const float* __restrict__ T,
    const float* __restrict__ gamma,
    float* __restrict__ out)
{
  // X tile: 128 rows x 128 k, bf16, A-fragment order (XOR bank swizzle).
  __shared__ uint4 Xs[32 * 64];   // 32 KB
  // W tile: direct copy of the pre-packed B-fragment tile for this d.
  __shared__ uint4 Gs[8 * 64];    // 8 KB
  __shared__ float2 stats[128];   // (rs*invT, mu*rs*invT) per local row

  const int d = blockIdx.x;
  const int t = threadIdx.x;
  const float invT = 1.0f / T[0];

  // ---------- Phase A: coalesced 8 KB W-tile copy ----------
  {
    const uint4* src = wp + (size_t)d * 512;
    Gs[t]       = src[t];
    Gs[t + 256] = src[t + 256];
  }

  // per-thread gamma registers (columns fixed per thread)
  const int c0 = (t & 15) * 8;
  const float4 ga = ((const float4*)(gamma + c0))[0];
  const float4 gb = ((const float4*)(gamma + c0))[1];

  const int wv = t >> 6, L = t & 63, quad = L >> 4;
  // per-thread LN-correction constants for the two h values this lane owns
  const int hA = L & 15;
  const float c1r0 = c1g[hA * NPOS + d];
  const float c1r1 = c1g[(hA + 16) * NPOS + d];
  const float er0  = eg[hA * NPOS + d];
  const float er1  = eg[(hA + 16) * NPOS + d];

  const short8* Gs8 = (const short8*)Gs;
  const short8* Xs8 = (const short8*)Xs;

  for (int ti = 0; ti < 4; ++ti) {
    // ---------- stage 128 rows of x: coalesced load, LN stats, gamma-fold ----------
    const int r16 = t >> 4;
#pragma unroll
    for (int it = 0; it < 8; ++it) {
      const int lrow = it * 16 + r16;                 // 0..127
      const float* xp = x + (size_t)(ti * 128 + lrow) * (NPOS * 128) + (size_t)d * 128 + c0;
      const float4 xa = ((const float4*)xp)[0];
      const float4 xb = ((const float4*)xp)[1];
      float s1 = xa.x + xa.y + xa.z + xa.w + xb.x + xb.y + xb.z + xb.w;
      float s2 = xa.x * xa.x + xa.y * xa.y + xa.z * xa.z + xa.w * xa.w
               + xb.x * xb.x + xb.y * xb.y + xb.z * xb.z + xb.w * xb.w;
#pragma unroll
      for (int msk = 1; msk < 16; msk <<= 1) {
        s1 += __shfl_xor(s1, msk, 64);
        s2 += __shfl_xor(s2, msk, 64);
      }
      if ((t & 15) == 0) {
        const float mu = s1 * (1.0f / 128.f);
        const float var = fmaf(-mu, mu, s2 * (1.0f / 128.f));
        const float rs = rsqrtf(var + LN_EPS);
        stats[lrow] = make_float2(rs * invT, mu * rs * invT);
      }
      uint4 v;
      v.x = packbf2(xa.x * ga.x, xa.y * ga.y);
      v.y = packbf2(xa.z * ga.z, xa.w * ga.w);
      v.z = packbf2(xb.x * gb.x, xb.y * gb.y);
      v.w = packbf2(xb.z * gb.z, xb.w * gb.w);
      const int ktile = (t & 15) >> 2, k8 = t & 3;
      const int c = k8 * 16 + r16;
      const int p = c ^ (k8 << 1) ^ ((ktile & 1) << 2) ^ (ktile >> 1);
      Xs[(it * 4 + ktile) * 64 + p] = v;
    }
    __syncthreads();

    // ---------- MFMA + fused LN/bias/T epilogue ----------
#pragma unroll
    for (int ht = 0; ht < 2; ++ht) {
      short8 bfr[4];
#pragma unroll
      for (int kt = 0; kt < 4; ++kt) bfr[kt] = Gs8[(kt * 2 + ht) * 64 + L];
      const int h = ht * 16 + hA;
      const float c1v = ht ? c1r1 : c1r0;
      const float ev  = ht ? er1 : er0;
#pragma unroll
      for (int rt = 0; rt < 2; ++rt) {
        const int rtile = wv * 2 + rt;
        floatx4 acc = {0.f, 0.f, 0.f, 0.f};
#pragma unroll
        for (int kt = 0; kt < 4; ++kt) {
          const int p = L ^ ((L >> 4) << 1) ^ ((kt & 1) << 2) ^ (kt >> 1);
          const short8 afr = Xs8[(rtile * 4 + kt) * 64 + p];
          acc = __builtin_amdgcn_mfma_f32_16x16x32_bf16(afr, bfr[kt], acc, 0, 0, 0);
        }
        const int lr0 = rtile * 16 + quad * 4;
#pragma unroll
        for (int r = 0; r < 4; ++r) {
          const float2 st = stats[lr0 + r];
          const float val = fmaf(st.x, acc[r], fmaf(-st.y, c1v, ev));
          out[(size_t)(ti * 128 + lr0 + r) * (NPOS * 32) + (size_t)d * 32 + h] = val;
        }
      }
    }
    __syncthreads();
  }
}

extern "C" void kernel_launch(void* const* d_in, const int* in_sizes, int n_in,
                              void* d_out, int out_size, void* d_ws, size_t ws_size,
                              hipStream_t stream) {
  const float* x     = (const float*)d_in[0];
  const float* w1    = (const float*)d_in[1];
  const float* b1    = (const float*)d_in[2];
  const float* T     = (const float*)d_in[3];
  const float* gamma = (const float*)d_in[4];
  const float* beta  = (const float*)d_in[5];
  float* out = (float*)d_out;

  uint4* wp  = (uint4*)d_ws;                                   // 16 MB
  float* c1g = (float*)((char*)d_ws + (size_t)16 * 1024 * 1024);      // 256 KB
  float* eg  = (float*)((char*)d_ws + (size_t)16 * 1024 * 1024 + 256 * 1024);

  hipLaunchKernelGGL(wpack_kernel, dim3(512), dim3(256), 0, stream, w1, wp);
  hipLaunchKernelGGL(c12_kernel, dim3(256), dim3(256), 0, stream,
                     w1, b1, T, gamma, beta, c1g, eg);
  hipLaunchKernelGGL(superlinear_kernel, dim3(NPOS), dim3(256), 0, stream,
                     x, wp, c1g, eg, T, gamma, out);
}